// Round 18
// baseline (176.117 us; speedup 1.0000x reference)
//
#include <hip/hip_runtime.h>

#define BB 4
#define TT 2048
#define CC 1024
#define HH 16
#define DD 64
#define MM (BB*TT)      // 8192 rows
#define N3 (3*CC)       // 3072
#define NTK 16          // K-tiles of 64 (K=1024)
#define QSCL 0.18033688011112043f   // 0.125 * log2(e), folded into Q at QKV epilogue

typedef unsigned short u16;
typedef __attribute__((ext_vector_type(8))) __bf16 bf16x8;
typedef __attribute__((ext_vector_type(4))) float f32x4;
typedef __attribute__((ext_vector_type(8))) u16 u16x8;
typedef __attribute__((ext_vector_type(4))) u16 u16x4;

__device__ __forceinline__ u16 f2bf(float f) {
  return __builtin_bit_cast(u16, (__bf16)f);   // RNE; compiler emits (packed) cvt
}

__device__ __forceinline__ void gload16(const void* g, void* lds) {
  __builtin_amdgcn_global_load_lds(
      (const __attribute__((address_space(1))) void*)g,
      (__attribute__((address_space(3))) void*)lds, 16, 0, 0);
}

// ---------------- fused prep: fp32->bf16 convert of x  +  both weight transposes ----------------
__global__ __launch_bounds__(256) void k_prep(const float* __restrict__ x,
                                              const float* __restrict__ wa, const float* __restrict__ wp,
                                              u16* __restrict__ Xb,
                                              u16* __restrict__ WaT, u16* __restrict__ WpT) {
  __shared__ float t[32][33];
  int bid = blockIdx.x;
  int tid = threadIdx.x;
  if (bid < 4096) {
    size_t i = ((size_t)bid * 256 + tid) * 8;
    f32x4 a = *(const f32x4*)(x + i);
    f32x4 b = *(const f32x4*)(x + i + 4);
    u16x8 o;
    o[0]=f2bf(a[0]); o[1]=f2bf(a[1]); o[2]=f2bf(a[2]); o[3]=f2bf(a[3]);
    o[4]=f2bf(b[0]); o[5]=f2bf(b[1]); o[6]=f2bf(b[2]); o[7]=f2bf(b[3]);
    *(u16x8*)(Xb + i) = o;
  } else {
    int t2 = bid - 4096;                 // 0..4095
    int gx = t2 & 127;                   // 96 wa + 32 wp column-tiles
    int rb = (t2 >> 7) * 32;
    const float* in; u16* out; int Cc, cb;
    if (gx < 96) { in = wa; out = WaT; Cc = N3; cb = gx * 32; }
    else         { in = wp; out = WpT; Cc = CC; cb = (gx - 96) * 32; }
    int tx = tid & 31, ty = tid >> 5;
    #pragma unroll
    for (int j = 0; j < 4; ++j)
      t[ty + j*8][tx] = in[(size_t)(rb + ty + j*8) * Cc + cb + tx];
    __syncthreads();
    #pragma unroll
    for (int j = 0; j < 4; ++j)
      out[(size_t)(cb + ty + j*8) * CC + rb + tx] = f2bf(t[tx][ty + j*8]);
  }
}

// ---------------- 128x256 GEMM engine, BK=64, 3-slot ring, counted vmcnt, 2-phase (FROZEN R10/R13) ----------------
__device__ __forceinline__ void gemm_ring(const u16* __restrict__ A, const u16* __restrict__ Bt,
                                          int mbase, int nbase,
                                          u16 (*As)[128*64], u16 (*Bs)[256*64],
                                          f32x4 acc[4][4]) {
  int tid = threadIdx.x;
  int lane = tid & 63;
  int wid = tid >> 6;
  int wm = (wid >> 2) * 64, wn = (wid & 3) * 64;
  int r = lane & 15, g = lane >> 4;

  auto STAGE_A = [&](int sl, int u) {
    int kb = u * 64;
    #pragma unroll
    for (int i = 0; i < 2; ++i) {
      int c = tid + 512*i;
      int row = c >> 3, ch = c & 7;
      int chs = ch ^ (row & 7);
      gload16(A + (size_t)(mbase + row)*CC + kb + chs*8, &As[sl][c*8]);
    }
  };
  auto STAGE_B1 = [&](int sl, int u, int i) {
    int kb = u * 64;
    int c = tid + 512*i;
    int row = c >> 3, ch = c & 7;
    int chs = ch ^ (row & 7);
    gload16(Bt + (size_t)(nbase + row)*CC + kb + chs*8, &Bs[sl][c*8]);
  };

  STAGE_A(0, 0); STAGE_B1(0, 0, 0); STAGE_B1(0, 0, 1); STAGE_B1(0, 0, 2); STAGE_B1(0, 0, 3);
  STAGE_A(1, 1); STAGE_B1(1, 1, 0); STAGE_B1(1, 1, 1); STAGE_B1(1, 1, 2); STAGE_B1(1, 1, 3);
  asm volatile("s_waitcnt vmcnt(6)" ::: "memory");
  __builtin_amdgcn_s_barrier();

  int sl = 0;
  for (int u = 0; u < NTK; ++u) {
    int s2 = sl + 2; if (s2 >= 3) s2 -= 3;
    bool pre = (u + 2 < NTK);
    #pragma unroll
    for (int ks = 0; ks < 2; ++ks) {
      bf16x8 af[4], bfr[4];
      #pragma unroll
      for (int mi = 0; mi < 4; ++mi)
        af[mi]  = *(const bf16x8*)&As[sl][(wm + mi*16 + r)*64 + (((ks*4 + g) ^ (r & 7)) << 3)];
      #pragma unroll
      for (int ni = 0; ni < 4; ++ni)
        bfr[ni] = *(const bf16x8*)&Bs[sl][(wn + ni*16 + r)*64 + (((ks*4 + g) ^ (r & 7)) << 3)];
      if (pre) {
        if (ks == 0) { STAGE_A(s2, u + 2); STAGE_B1(s2, u + 2, 0); }
        else         { STAGE_B1(s2, u + 2, 1); STAGE_B1(s2, u + 2, 2); STAGE_B1(s2, u + 2, 3); }
      }
      __builtin_amdgcn_s_barrier();
      __builtin_amdgcn_s_setprio(1);
      #pragma unroll
      for (int mi = 0; mi < 4; ++mi)
        #pragma unroll
        for (int ni = 0; ni < 4; ++ni)
          acc[mi][ni] = __builtin_amdgcn_mfma_f32_16x16x32_bf16(af[mi], bfr[ni], acc[mi][ni], 0, 0, 0);
      __builtin_amdgcn_s_setprio(0);
      if (ks == 1) {
        if (pre) asm volatile("s_waitcnt vmcnt(6)" ::: "memory");
        else     asm volatile("s_waitcnt vmcnt(0)" ::: "memory");
      }
      __builtin_amdgcn_s_barrier();
    }
    ++sl; if (sl >= 3) sl -= 3;
  }
}

// XCD-chunked bijective bid map (NBX = 64)
__device__ __forceinline__ void grid_map(int bid, int& bx, int& by) {
  int xcd = bid & 7;
  int idx = bid >> 3;
  bx = xcd * 8 + (idx & 7);
  by = idx >> 3;
}

// ---------------- QKV GEMM: Q (pre-scaled) / K -> [B,H,T,D], V -> [B,H,D,T] ----------------
__global__ __launch_bounds__(512) void k_gemm_qkv(const u16* __restrict__ Xb, const u16* __restrict__ WaT,
                                                  const float* __restrict__ b_attn,
                                                  u16* __restrict__ Qh, u16* __restrict__ Kh,
                                                  u16* __restrict__ Vt) {
  __shared__ u16 As[3][128*64];
  __shared__ u16 Bs[3][256*64];
  f32x4 acc[4][4] = {};
  int bx, by; grid_map(blockIdx.x, bx, by);
  int mbase = bx * 128, nbase = by * 256;
  gemm_ring(Xb, WaT, mbase, nbase, As, Bs, acc);
  int lane = threadIdx.x & 63, wid = threadIdx.x >> 6;
  int wm = (wid >> 2) * 64, wn = (wid & 3) * 64;
  int r = lane & 15, g = lane >> 4;
  int which = nbase >> 10;            // 0=Q 1=K 2=V, uniform per block
  if (which < 2) {
    u16* dst = which == 0 ? Qh : Kh;
    float scl = which == 0 ? QSCL : 1.0f;
    #pragma unroll
    for (int mi = 0; mi < 4; ++mi)
      #pragma unroll
      for (int ni = 0; ni < 4; ++ni)
        #pragma unroll
        for (int reg = 0; reg < 4; ++reg) {
          int m = mbase + wm + mi*16 + 4*g + reg;
          int n = nbase + wn + ni*16 + r;
          float v = (acc[mi][ni][reg] + b_attn[n]) * scl;
          int ccol = n & (CC - 1);
          int h = ccol >> 6, d = ccol & 63;
          int bb = m >> 11, t = m & (TT - 1);
          dst[((size_t)(bb*HH + h)*TT + t)*DD + d] = f2bf(v);
        }
  } else {
    #pragma unroll
    for (int mi = 0; mi < 4; ++mi)
      #pragma unroll
      for (int ni = 0; ni < 4; ++ni) {
        int m0 = mbase + wm + mi*16 + 4*g;
        int n = nbase + wn + ni*16 + r;
        float bn = b_attn[n];
        int ccol = n & (CC - 1);
        int h = ccol >> 6, d = ccol & 63;
        int bb = m0 >> 11, t0 = m0 & (TT - 1);
        u16x4 pk;
        #pragma unroll
        for (int reg = 0; reg < 4; ++reg)
          pk[reg] = f2bf(acc[mi][ni][reg] + bn);
        *(u16x4*)&Vt[((size_t)(bb*HH + h)*DD + d)*TT + t0] = pk;
      }
  }
}

// ---------------- projection GEMM: out = Y @ Wp + b_proj (fp32 out) ----------------
__global__ __launch_bounds__(512) void k_gemm_proj(const u16* __restrict__ Yh, const u16* __restrict__ WpT,
                                                   const float* __restrict__ b_proj,
                                                   float* __restrict__ out) {
  __shared__ u16 As[3][128*64];
  __shared__ u16 Bs[3][256*64];
  f32x4 acc[4][4] = {};
  int bx, by; grid_map(blockIdx.x, bx, by);
  int mbase = bx * 128, nbase = by * 256;
  gemm_ring(Yh, WpT, mbase, nbase, As, Bs, acc);
  int lane = threadIdx.x & 63, wid = threadIdx.x >> 6;
  int wm = (wid >> 2) * 64, wn = (wid & 3) * 64;
  int r = lane & 15, g = lane >> 4;
  #pragma unroll
  for (int mi = 0; mi < 4; ++mi)
    #pragma unroll
    for (int ni = 0; ni < 4; ++ni)
      #pragma unroll
      for (int reg = 0; reg < 4; ++reg) {
        int m = mbase + wm + mi*16 + 4*g + reg;
        int n = nbase + wn + ni*16 + r;
        out[(size_t)m*CC + n] = acc[mi][ni][reg] + b_proj[n];
      }
}

// ---------------- flash attention: FUSED hi/lo q-tile pair, one K/V pass ----------------
// R18 = R13 structure, but both q-tiles {15-p, p} processed in ONE k-loop: lo's key range
// ((p+1)*128) is a strict prefix of hi's ((16-p)*128), so one staging pass covers both.
// Staged blocks/pair: 17 -> 16-p (mean 12.5, -26% traffic+syncs); during overlap each wave
// computes BOTH tiles per staged block (2x independent work per sync step = latency hiding).
__global__ __launch_bounds__(256) void k_attn(const u16* __restrict__ Qh, const u16* __restrict__ Kh,
                                              const u16* __restrict__ Vtg, u16* __restrict__ Yh) {
  __shared__ u16 Ks[2][128*64];   // [key128][d64], chunk-swizzled
  __shared__ u16 Vs[2][64*128];   // [d64][key128], chunk-swizzled
  __shared__ u16 Pl[4][32*64];
  int bid = blockIdx.x;
  int bh = (bid & 7) * 8 + (bid >> 6);   // XCD x handles bh in [8x, 8x+8)
  int p  = (bid >> 3) & 7;
  int b = bh >> 4, h = bh & 15;
  int tid = threadIdx.x, lane = tid & 63, w = tid >> 6;
  int r = lane & 15, g = lane >> 4;
  size_t hoff = (size_t)bh * TT * DD;
  u16* pw = Pl[w];

  bf16x8 ones;
  #pragma unroll
  for (int e = 0; e < 8; ++e) ones[e] = (__bf16)1.0f;

  // ---- per-thread staging offsets (elements), computed ONCE ----
  int koff[4], voff[4], kld[4], vld[4];
  #pragma unroll
  for (int i = 0; i < 4; ++i) {
    int c = tid + 256*i;
    int krow = c >> 3, kch = c & 7;
    koff[i] = krow*DD + (kch ^ (krow & 7))*8;
    int vrow = c >> 4, vch = c & 15;
    voff[i] = vrow*TT + ((vch ^ (vrow & 7)))*8;
    kld[i] = c*8; vld[i] = c*8;
  }
  const u16* Kg0 = Kh  + hoff;
  const u16* Vg0 = Vtg + hoff;

  auto STAGE = [&](int bsel, int kb) {
    const u16* kbase = Kg0 + (size_t)kb * (128*DD);
    const u16* vbase = Vg0 + (size_t)kb * 128;
    u16* Kd = bsel ? &Ks[1][0] : &Ks[0][0];
    u16* Vd = bsel ? &Vs[1][0] : &Vs[0][0];
    #pragma unroll
    for (int i = 0; i < 4; ++i) gload16(kbase + koff[i], Kd + kld[i]);
    #pragma unroll
    for (int i = 0; i < 4; ++i) gload16(vbase + voff[i], Vd + vld[i]);
  };

  int qtH = 15 - p, qtL = p;
  int qrow0H = qtH*128 + w*32, qrow0L = qtL*128 + w*32;
  int nkb = qtH + 1;                     // covers lo too (p+1 <= 16-p for p<=7)

  bf16x8 qfH[2][2], qfL[2][2];
  #pragma unroll
  for (int ni = 0; ni < 2; ++ni)
    #pragma unroll
    for (int ks = 0; ks < 2; ++ks) {
      qfH[ni][ks] = *(const bf16x8*)(Qh + hoff + (size_t)(qrow0H + ni*16 + r)*DD + ks*32 + g*8);
      qfL[ni][ks] = *(const bf16x8*)(Qh + hoff + (size_t)(qrow0L + ni*16 + r)*DD + ks*32 + g*8);
    }

  f32x4 oH[2][4] = {}, oL[2][4] = {};
  f32x4 laccH[2] = {}, laccL[2] = {};

  // per-tile compute body (statically inlined; all indices compile-time in unrolled loops)
  auto TILE = [&](int qrow0, bf16x8 (&qf)[2][2], f32x4 (&o)[2][4], f32x4 (&lacc)[2],
                  int keybase, int kc, int buf) {
    f32x4 s[2][4] = {};
    __builtin_amdgcn_s_setprio(1);
    #pragma unroll
    for (int nf = 0; nf < 4; ++nf)
      #pragma unroll
      for (int ks = 0; ks < 2; ++ks) {
        bf16x8 kf = *(const bf16x8*)&Ks[buf][(kc*64 + nf*16 + r)*64 + (((ks*4 + g) ^ (r & 7)) << 3)];
        #pragma unroll
        for (int ni = 0; ni < 2; ++ni)
          s[ni][nf] = __builtin_amdgcn_mfma_f32_16x16x32_bf16(kf, qf[ni][ks], s[ni][nf], 0, 0, 0);
      }
    __builtin_amdgcn_s_setprio(0);
    bool need_mask = (keybase + 63 > qrow0);
    if (need_mask) {
      #pragma unroll
      for (int ni = 0; ni < 2; ++ni)
        #pragma unroll
        for (int nf = 0; nf < 4; ++nf)
          #pragma unroll
          for (int reg = 0; reg < 4; ++reg) {
            int key = keybase + nf*16 + 4*g + reg;
            int qrow = qrow0 + ni*16 + r;
            float sv = (key > qrow) ? -1e30f : s[ni][nf][reg];
            s[ni][nf][reg] = __builtin_amdgcn_exp2f(sv);
          }
    } else {
      #pragma unroll
      for (int ni = 0; ni < 2; ++ni)
        #pragma unroll
        for (int nf = 0; nf < 4; ++nf)
          #pragma unroll
          for (int reg = 0; reg < 4; ++reg)
            s[ni][nf][reg] = __builtin_amdgcn_exp2f(s[ni][nf][reg]);
    }
    #pragma unroll
    for (int ni = 0; ni < 2; ++ni)
      #pragma unroll
      for (int nf = 0; nf < 4; ++nf) {
        int qh_ = ni*16 + r;
        int chunk = 2*nf + (g >> 1);
        u16x4 pk;
        #pragma unroll
        for (int reg = 0; reg < 4; ++reg) pk[reg] = f2bf(s[ni][nf][reg]);
        *(u16x4*)&pw[qh_*64 + ((chunk ^ (qh_ & 7)) << 3) + ((g & 1) << 2)] = pk;
      }
    __builtin_amdgcn_s_setprio(1);
    #pragma unroll
    for (int ks = 0; ks < 2; ++ks) {
      bf16x8 pb[2];
      #pragma unroll
      for (int ni = 0; ni < 2; ++ni)
        pb[ni] = *(const bf16x8*)&pw[(ni*16 + r)*64 + (((ks*4 + g) ^ (r & 7)) << 3)];
      #pragma unroll
      for (int nf2 = 0; nf2 < 4; ++nf2) {
        bf16x8 vf = *(const bf16x8*)&Vs[buf][(nf2*16 + r)*128 + (((kc*8 + ks*4 + g) ^ (r & 7)) << 3)];
        #pragma unroll
        for (int ni = 0; ni < 2; ++ni)
          o[ni][nf2] = __builtin_amdgcn_mfma_f32_16x16x32_bf16(vf, pb[ni], o[ni][nf2], 0, 0, 0);
      }
      #pragma unroll
      for (int ni = 0; ni < 2; ++ni)
        lacc[ni] = __builtin_amdgcn_mfma_f32_16x16x32_bf16(ones, pb[ni], lacc[ni], 0, 0, 0);
    }
    __builtin_amdgcn_s_setprio(0);
  };

  STAGE(0, 0);
  __syncthreads();
  int buf = 0;

  for (int kb = 0; kb < nkb; ++kb) {
    if (kb + 1 < nkb) STAGE(buf ^ 1, kb + 1);

    #pragma unroll
    for (int kc = 0; kc < 2; ++kc) {
      int keybase = kb*128 + kc*64;
      if (keybase <= qrow0H + 31) TILE(qrow0H, qfH, oH, laccH, keybase, kc, buf);
      if (keybase <= qrow0L + 31) TILE(qrow0L, qfL, oL, laccL, keybase, kc, buf);
    }
    __syncthreads();
    buf ^= 1;
  }

  // ---- epilogue: both tiles; O^T col=q (r), row=d; pack 4 d per 8B store ----
  #pragma unroll
  for (int ni = 0; ni < 2; ++ni) {
    float invH = 1.0f / laccH[ni][0];
    float invL = 1.0f / laccL[ni][0];
    int tH = qrow0H + ni*16 + r;
    int tL = qrow0L + ni*16 + r;
    #pragma unroll
    for (int nf2 = 0; nf2 < 4; ++nf2) {
      u16x4 pkH, pkL;
      #pragma unroll
      for (int reg = 0; reg < 4; ++reg) {
        pkH[reg] = f2bf(oH[ni][nf2][reg] * invH);
        pkL[reg] = f2bf(oL[ni][nf2][reg] * invL);
      }
      *(u16x4*)&Yh[((size_t)b*TT + tH)*CC + h*DD + nf2*16 + 4*g] = pkH;
      *(u16x4*)&Yh[((size_t)b*TT + tL)*CC + h*DD + nf2*16 + 4*g] = pkL;
    }
  }
}

extern "C" void kernel_launch(void* const* d_in, const int* in_sizes, int n_in,
                              void* d_out, int out_size, void* d_ws, size_t ws_size,
                              hipStream_t stream) {
  const float* x      = (const float*)d_in[0];
  const float* w_attn = (const float*)d_in[1];
  const float* b_attn = (const float*)d_in[2];
  const float* w_proj = (const float*)d_in[3];
  const float* b_proj = (const float*)d_in[4];
  float* out = (float*)d_out;

  u16* Xb  = (u16*)d_ws;                       // [8192][1024] bf16
  u16* WaT = Xb  + (size_t)MM*CC;              // [3072][1024] bf16 (w_attn^T)
  u16* WpT = WaT + (size_t)N3*CC;              // [1024][1024] bf16 (w_proj^T)
  u16* Qh  = WpT + (size_t)CC*CC;              // [B,H,T,D] bf16 (pre-scaled)
  u16* Kh  = Qh  + (size_t)BB*HH*TT*DD;        // [B,H,T,D] bf16
  u16* Vt  = Kh  + (size_t)BB*HH*TT*DD;        // [B,H,D,T] bf16 (transposed)
  u16* Yh  = Vt  + (size_t)BB*HH*TT*DD;        // [8192][1024] bf16

  k_prep<<<dim3(8192), dim3(256), 0, stream>>>(x, w_attn, w_proj, Xb, WaT, WpT);
  k_gemm_qkv<<<dim3((MM/128)*(N3/256)), dim3(512), 0, stream>>>(Xb, WaT, b_attn, Qh, Kh, Vt);
  k_attn<<<dim3(BB*HH*8), dim3(256), 0, stream>>>(Qh, Kh, Vt, Yh);
  k_gemm_proj<<<dim3((MM/128)*(CC/256)), dim3(512), 0, stream>>>(Yh, WpT, b_proj, out);
}

// Round 19
// 155.142 us; speedup vs baseline: 1.1352x; 1.1352x over previous
//
#include <hip/hip_runtime.h>

#define BB 4
#define TT 2048
#define CC 1024
#define HH 16
#define DD 64
#define MM (BB*TT)      // 8192 rows
#define N3 (3*CC)       // 3072
#define NTK 16          // K-tiles of 64 (K=1024)
#define QSCL 0.18033688011112043f   // 0.125 * log2(e), folded into Q at QKV epilogue

typedef unsigned short u16;
typedef __attribute__((ext_vector_type(8))) __bf16 bf16x8;
typedef __attribute__((ext_vector_type(4))) float f32x4;
typedef __attribute__((ext_vector_type(8))) u16 u16x8;
typedef __attribute__((ext_vector_type(4))) u16 u16x4;

__device__ __forceinline__ u16 f2bf(float f) {
  return __builtin_bit_cast(u16, (__bf16)f);   // RNE; compiler emits (packed) cvt
}

__device__ __forceinline__ void gload16(const void* g, void* lds) {
  __builtin_amdgcn_global_load_lds(
      (const __attribute__((address_space(1))) void*)g,
      (__attribute__((address_space(3))) void*)lds, 16, 0, 0);
}

// ---------------- fused prep: fp32->bf16 convert of x  +  both weight transposes ----------------
// blocks [0,4096): cvt 8 elems/thread; blocks [4096,8192): 32x32 transpose tiles.
__global__ __launch_bounds__(256) void k_prep(const float* __restrict__ x,
                                              const float* __restrict__ wa, const float* __restrict__ wp,
                                              u16* __restrict__ Xb,
                                              u16* __restrict__ WaT, u16* __restrict__ WpT) {
  __shared__ float t[32][33];
  int bid = blockIdx.x;
  int tid = threadIdx.x;
  if (bid < 4096) {
    size_t i = ((size_t)bid * 256 + tid) * 8;
    f32x4 a = *(const f32x4*)(x + i);
    f32x4 b = *(const f32x4*)(x + i + 4);
    u16x8 o;
    o[0]=f2bf(a[0]); o[1]=f2bf(a[1]); o[2]=f2bf(a[2]); o[3]=f2bf(a[3]);
    o[4]=f2bf(b[0]); o[5]=f2bf(b[1]); o[6]=f2bf(b[2]); o[7]=f2bf(b[3]);
    *(u16x8*)(Xb + i) = o;
  } else {
    int t2 = bid - 4096;                 // 0..4095
    int gx = t2 & 127;                   // 0..127 (96 wa + 32 wp column-tiles)
    int rb = (t2 >> 7) * 32;             // 0..31 row-tiles
    const float* in; u16* out; int Cc, cb;
    if (gx < 96) { in = wa; out = WaT; Cc = N3; cb = gx * 32; }
    else         { in = wp; out = WpT; Cc = CC; cb = (gx - 96) * 32; }
    int tx = tid & 31, ty = tid >> 5;    // (32,8) decode
    #pragma unroll
    for (int j = 0; j < 4; ++j)
      t[ty + j*8][tx] = in[(size_t)(rb + ty + j*8) * Cc + cb + tx];
    __syncthreads();
    #pragma unroll
    for (int j = 0; j < 4; ++j)
      out[(size_t)(cb + ty + j*8) * CC + rb + tx] = f2bf(t[tx][ty + j*8]);
  }
}

// ---------------- 128x256 GEMM engine, BK=64, 3-slot ring, counted vmcnt, 2-phase ----------------
// PROVEN R10/R13 config (best measured: qkv 72us, total 155.2). Closed-out negatives:
// sched_barrier/lgkmcnt pins (R8 -16%), swapped-operand ring (R14/R15 +9us), BK=64+2barrier (R4),
// fused attn pair (R18: reg pressure > 256 -> occupancy halved).
__device__ __forceinline__ void gemm_ring(const u16* __restrict__ A, const u16* __restrict__ Bt,
                                          int mbase, int nbase,
                                          u16 (*As)[128*64], u16 (*Bs)[256*64],
                                          f32x4 acc[4][4]) {
  int tid = threadIdx.x;
  int lane = tid & 63;
  int wid = tid >> 6;
  int wm = (wid >> 2) * 64, wn = (wid & 3) * 64;
  int r = lane & 15, g = lane >> 4;

  auto STAGE_A = [&](int sl, int u) {
    int kb = u * 64;
    #pragma unroll
    for (int i = 0; i < 2; ++i) {
      int c = tid + 512*i;                 // A: 1024 chunks (128 rows x 8)
      int row = c >> 3, ch = c & 7;
      int chs = ch ^ (row & 7);
      gload16(A + (size_t)(mbase + row)*CC + kb + chs*8, &As[sl][c*8]);
    }
  };
  auto STAGE_B1 = [&](int sl, int u, int i) {
    int kb = u * 64;
    int c = tid + 512*i;                   // B: 2048 chunks (256 rows x 8)
    int row = c >> 3, ch = c & 7;
    int chs = ch ^ (row & 7);
    gload16(Bt + (size_t)(nbase + row)*CC + kb + chs*8, &Bs[sl][c*8]);
  };

  STAGE_A(0, 0); STAGE_B1(0, 0, 0); STAGE_B1(0, 0, 1); STAGE_B1(0, 0, 2); STAGE_B1(0, 0, 3);
  STAGE_A(1, 1); STAGE_B1(1, 1, 0); STAGE_B1(1, 1, 1); STAGE_B1(1, 1, 2); STAGE_B1(1, 1, 3);
  asm volatile("s_waitcnt vmcnt(6)" ::: "memory");   // slot0 landed; slot1 in flight
  __builtin_amdgcn_s_barrier();

  int sl = 0;
  for (int u = 0; u < NTK; ++u) {
    int s2 = sl + 2; if (s2 >= 3) s2 -= 3;
    bool pre = (u + 2 < NTK);
    #pragma unroll
    for (int ks = 0; ks < 2; ++ks) {
      // ---- ds-load register subtile for this phase ----
      bf16x8 af[4], bfr[4];
      #pragma unroll
      for (int mi = 0; mi < 4; ++mi)
        af[mi]  = *(const bf16x8*)&As[sl][(wm + mi*16 + r)*64 + (((ks*4 + g) ^ (r & 7)) << 3)];
      #pragma unroll
      for (int ni = 0; ni < 4; ++ni)
        bfr[ni] = *(const bf16x8*)&Bs[sl][(wn + ni*16 + r)*64 + (((ks*4 + g) ^ (r & 7)) << 3)];
      // ---- stage issue: half of next-tile loads per phase ----
      if (pre) {
        if (ks == 0) { STAGE_A(s2, u + 2); STAGE_B1(s2, u + 2, 0); }
        else         { STAGE_B1(s2, u + 2, 1); STAGE_B1(s2, u + 2, 2); STAGE_B1(s2, u + 2, 3); }
      }
      __builtin_amdgcn_s_barrier();
      // (compiler inserts lgkmcnt before first MFMA use)
      __builtin_amdgcn_s_setprio(1);
      #pragma unroll
      for (int mi = 0; mi < 4; ++mi)
        #pragma unroll
        for (int ni = 0; ni < 4; ++ni)
          acc[mi][ni] = __builtin_amdgcn_mfma_f32_16x16x32_bf16(af[mi], bfr[ni], acc[mi][ni], 0, 0, 0);
      __builtin_amdgcn_s_setprio(0);
      if (ks == 1) {
        if (pre) asm volatile("s_waitcnt vmcnt(6)" ::: "memory");  // (u+1) landed, (u+2) in flight
        else     asm volatile("s_waitcnt vmcnt(0)" ::: "memory");  // tail drain
      }
      __builtin_amdgcn_s_barrier();
    }
    ++sl; if (sl >= 3) sl -= 3;
  }
}

// XCD-chunked bijective bid map (NBX = 64): 8 m-blocks per XCD -> A panels L2-resident
__device__ __forceinline__ void grid_map(int bid, int& bx, int& by) {
  int xcd = bid & 7;
  int idx = bid >> 3;
  bx = xcd * 8 + (idx & 7);
  by = idx >> 3;
}

// ---------------- QKV GEMM: Q (pre-scaled) / K -> [B,H,T,D], V -> [B,H,D,T] ----------------
__global__ __launch_bounds__(512) void k_gemm_qkv(const u16* __restrict__ Xb, const u16* __restrict__ WaT,
                                                  const float* __restrict__ b_attn,
                                                  u16* __restrict__ Qh, u16* __restrict__ Kh,
                                                  u16* __restrict__ Vt) {
  __shared__ u16 As[3][128*64];
  __shared__ u16 Bs[3][256*64];
  f32x4 acc[4][4] = {};
  int bx, by; grid_map(blockIdx.x, bx, by);
  int mbase = bx * 128, nbase = by * 256;
  gemm_ring(Xb, WaT, mbase, nbase, As, Bs, acc);
  int lane = threadIdx.x & 63, wid = threadIdx.x >> 6;
  int wm = (wid >> 2) * 64, wn = (wid & 3) * 64;
  int r = lane & 15, g = lane >> 4;
  int which = nbase >> 10;            // 0=Q 1=K 2=V, uniform per block
  if (which < 2) {
    u16* dst = which == 0 ? Qh : Kh;
    float scl = which == 0 ? QSCL : 1.0f;   // fold softmax scale into Q
    #pragma unroll
    for (int mi = 0; mi < 4; ++mi)
      #pragma unroll
      for (int ni = 0; ni < 4; ++ni)
        #pragma unroll
        for (int reg = 0; reg < 4; ++reg) {
          int m = mbase + wm + mi*16 + 4*g + reg;   // C/D: row=(lane>>4)*4+reg, col=lane&15
          int n = nbase + wn + ni*16 + r;
          float v = (acc[mi][ni][reg] + b_attn[n]) * scl;
          int ccol = n & (CC - 1);
          int h = ccol >> 6, d = ccol & 63;
          int bb = m >> 11, t = m & (TT - 1);
          dst[((size_t)(bb*HH + h)*TT + t)*DD + d] = f2bf(v);
        }
  } else {
    // V: 4 consecutive t (regs) -> one 8B store
    #pragma unroll
    for (int mi = 0; mi < 4; ++mi)
      #pragma unroll
      for (int ni = 0; ni < 4; ++ni) {
        int m0 = mbase + wm + mi*16 + 4*g;
        int n = nbase + wn + ni*16 + r;
        float bn = b_attn[n];
        int ccol = n & (CC - 1);
        int h = ccol >> 6, d = ccol & 63;
        int bb = m0 >> 11, t0 = m0 & (TT - 1);
        u16x4 pk;
        #pragma unroll
        for (int reg = 0; reg < 4; ++reg)
          pk[reg] = f2bf(acc[mi][ni][reg] + bn);
        *(u16x4*)&Vt[((size_t)(bb*HH + h)*DD + d)*TT + t0] = pk;
      }
  }
}

// ---------------- projection GEMM: out = Y @ Wp + b_proj (fp32 out) ----------------
__global__ __launch_bounds__(512) void k_gemm_proj(const u16* __restrict__ Yh, const u16* __restrict__ WpT,
                                                   const float* __restrict__ b_proj,
                                                   float* __restrict__ out) {
  __shared__ u16 As[3][128*64];
  __shared__ u16 Bs[3][256*64];
  f32x4 acc[4][4] = {};
  int bx, by; grid_map(blockIdx.x, bx, by);
  int mbase = bx * 128, nbase = by * 256;
  gemm_ring(Yh, WpT, mbase, nbase, As, Bs, acc);
  int lane = threadIdx.x & 63, wid = threadIdx.x >> 6;
  int wm = (wid >> 2) * 64, wn = (wid & 3) * 64;
  int r = lane & 15, g = lane >> 4;
  #pragma unroll
  for (int mi = 0; mi < 4; ++mi)
    #pragma unroll
    for (int ni = 0; ni < 4; ++ni)
      #pragma unroll
      for (int reg = 0; reg < 4; ++reg) {
        int m = mbase + wm + mi*16 + 4*g + reg;
        int n = nbase + wn + ni*16 + r;
        out[(size_t)m*CC + n] = acc[mi][ni][reg] + b_proj[n];
      }
}

// ---------------- flash attention: paired q-tiles, 128-key staging, hoisted addresses (R13 exact) ----------------
__global__ __launch_bounds__(256) void k_attn(const u16* __restrict__ Qh, const u16* __restrict__ Kh,
                                              const u16* __restrict__ Vtg, u16* __restrict__ Yh) {
  __shared__ u16 Ks[2][128*64];   // [key128][d64], chunk-swizzled
  __shared__ u16 Vs[2][64*128];   // [d64][key128], chunk-swizzled
  __shared__ u16 Pl[4][32*64];
  int bid = blockIdx.x;
  int bh = (bid & 7) * 8 + (bid >> 6);   // XCD x handles bh in [8x, 8x+8)
  int p  = (bid >> 3) & 7;
  int b = bh >> 4, h = bh & 15;
  int tid = threadIdx.x, lane = tid & 63, w = tid >> 6;
  int r = lane & 15, g = lane >> 4;
  size_t hoff = (size_t)bh * TT * DD;
  u16* pw = Pl[w];

  bf16x8 ones;
  #pragma unroll
  for (int e = 0; e < 8; ++e) ones[e] = (__bf16)1.0f;

  // ---- per-thread staging offsets (elements), computed ONCE ----
  int koff[4], voff[4], kld[4], vld[4];
  #pragma unroll
  for (int i = 0; i < 4; ++i) {
    int c = tid + 256*i;
    int krow = c >> 3, kch = c & 7;
    koff[i] = krow*DD + (kch ^ (krow & 7))*8;      // within 128-key K window
    int vrow = c >> 4, vch = c & 15;
    voff[i] = vrow*TT + ((vch ^ (vrow & 7)))*8;    // within 128-key V^T window
    kld[i] = c*8; vld[i] = c*8;
  }
  const u16* Kg0 = Kh  + hoff;
  const u16* Vg0 = Vtg + hoff;

  auto STAGE = [&](int bsel, int kb) {   // kb in 128-key units
    const u16* kbase = Kg0 + (size_t)kb * (128*DD);
    const u16* vbase = Vg0 + (size_t)kb * 128;
    u16* Kd = bsel ? &Ks[1][0] : &Ks[0][0];
    u16* Vd = bsel ? &Vs[1][0] : &Vs[0][0];
    #pragma unroll
    for (int i = 0; i < 4; ++i) gload16(kbase + koff[i], Kd + kld[i]);
    #pragma unroll
    for (int i = 0; i < 4; ++i) gload16(vbase + voff[i], Vd + vld[i]);
  };

  for (int ph = 0; ph < 2; ++ph) {
    int qt = ph == 0 ? (15 - p) : p;
    int qrow0 = qt*128 + w*32;
    int nkb = qt + 1;                    // 128-key blocks

    bf16x8 qf[2][2];                     // B-operand: lane r = q-row, g*8 = d-quarter
    #pragma unroll
    for (int ni = 0; ni < 2; ++ni)
      #pragma unroll
      for (int ks = 0; ks < 2; ++ks)
        qf[ni][ks] = *(const bf16x8*)(Qh + hoff + (size_t)(qrow0 + ni*16 + r)*DD + ks*32 + g*8);

    f32x4 o[2][4] = {};                  // O^T: [ni][d-frag], col=q, row=d
    f32x4 lacc[2] = {};

    STAGE(0, 0);
    __syncthreads();
    int buf = 0;

    for (int kb = 0; kb < nkb; ++kb) {
      if (kb + 1 < nkb) STAGE(buf ^ 1, kb + 1);

      #pragma unroll
      for (int kc = 0; kc < 2; ++kc) {
        int keybase = kb*128 + kc*64;
        if (keybase <= qrow0 + 31) {         // sub-chunk not fully masked
          // ---- S^T = K Q^T : row=key (4 frags), col=q (2 frags) ----
          f32x4 s[2][4] = {};                // s[ni][nf]
          __builtin_amdgcn_s_setprio(1);
          #pragma unroll
          for (int nf = 0; nf < 4; ++nf)
            #pragma unroll
            for (int ks = 0; ks < 2; ++ks) {
              bf16x8 kf = *(const bf16x8*)&Ks[buf][(kc*64 + nf*16 + r)*64 + (((ks*4 + g) ^ (r & 7)) << 3)];
              #pragma unroll
              for (int ni = 0; ni < 2; ++ni)
                s[ni][nf] = __builtin_amdgcn_mfma_f32_16x16x32_bf16(kf, qf[ni][ks], s[ni][nf], 0, 0, 0);
            }
          __builtin_amdgcn_s_setprio(0);
          // ---- exp2; mask VALU only on diagonal blocks (wave-uniform branch) ----
          bool need_mask = (keybase + 63 > qrow0);
          if (need_mask) {
            #pragma unroll
            for (int ni = 0; ni < 2; ++ni)
              #pragma unroll
              for (int nf = 0; nf < 4; ++nf)
                #pragma unroll
                for (int reg = 0; reg < 4; ++reg) {
                  int key = keybase + nf*16 + 4*g + reg;
                  int qrow = qrow0 + ni*16 + r;
                  float sv = (key > qrow) ? -1e30f : s[ni][nf][reg];
                  s[ni][nf][reg] = __builtin_amdgcn_exp2f(sv);
                }
          } else {
            #pragma unroll
            for (int ni = 0; ni < 2; ++ni)
              #pragma unroll
              for (int nf = 0; nf < 4; ++nf)
                #pragma unroll
                for (int reg = 0; reg < 4; ++reg)
                  s[ni][nf][reg] = __builtin_amdgcn_exp2f(s[ni][nf][reg]);
          }
          // ---- P -> per-wave LDS: packed 8B writes; same-wave reuse across kc ----
          #pragma unroll
          for (int ni = 0; ni < 2; ++ni)
            #pragma unroll
            for (int nf = 0; nf < 4; ++nf) {
              int qh_ = ni*16 + r;                       // q-row within 32
              int chunk = 2*nf + (g >> 1);               // 16B chunk = key>>3 (within 64)
              u16x4 pk;
              #pragma unroll
              for (int reg = 0; reg < 4; ++reg) pk[reg] = f2bf(s[ni][nf][reg]);
              *(u16x4*)&pw[qh_*64 + ((chunk ^ (qh_ & 7)) << 3) + ((g & 1) << 2)] = pk;
            }
          __builtin_amdgcn_s_setprio(1);
          #pragma unroll
          for (int ks = 0; ks < 2; ++ks) {
            bf16x8 pb[2];
            #pragma unroll
            for (int ni = 0; ni < 2; ++ni)
              pb[ni] = *(const bf16x8*)&pw[(ni*16 + r)*64 + (((ks*4 + g) ^ (r & 7)) << 3)];
            #pragma unroll
            for (int nf2 = 0; nf2 < 4; ++nf2) {
              bf16x8 vf = *(const bf16x8*)&Vs[buf][(nf2*16 + r)*128 + (((kc*8 + ks*4 + g) ^ (r & 7)) << 3)];
              #pragma unroll
              for (int ni = 0; ni < 2; ++ni)
                o[ni][nf2] = __builtin_amdgcn_mfma_f32_16x16x32_bf16(vf, pb[ni], o[ni][nf2], 0, 0, 0);
            }
            #pragma unroll
            for (int ni = 0; ni < 2; ++ni)
              lacc[ni] = __builtin_amdgcn_mfma_f32_16x16x32_bf16(ones, pb[ni], lacc[ni], 0, 0, 0);
          }
          __builtin_amdgcn_s_setprio(0);
        }
      }
      __syncthreads();
      buf ^= 1;
    }

    // ---- epilogue: O^T col=q (r), row=d; pack 4 d per 8B store ----
    #pragma unroll
    for (int ni = 0; ni < 2; ++ni) {
      float inv = 1.0f / lacc[ni][0];
      int t = qrow0 + ni*16 + r;
      #pragma unroll
      for (int nf2 = 0; nf2 < 4; ++nf2) {
        u16x4 pk;
        #pragma unroll
        for (int reg = 0; reg < 4; ++reg)
          pk[reg] = f2bf(o[ni][nf2][reg] * inv);
        *(u16x4*)&Yh[((size_t)b*TT + t)*CC + h*DD + nf2*16 + 4*g] = pk;
      }
    }
  }
}

extern "C" void kernel_launch(void* const* d_in, const int* in_sizes, int n_in,
                              void* d_out, int out_size, void* d_ws, size_t ws_size,
                              hipStream_t stream) {
  const float* x      = (const float*)d_in[0];
  const float* w_attn = (const float*)d_in[1];
  const float* b_attn = (const float*)d_in[2];
  const float* w_proj = (const float*)d_in[3];
  const float* b_proj = (const float*)d_in[4];
  float* out = (float*)d_out;

  u16* Xb  = (u16*)d_ws;                       // [8192][1024] bf16
  u16* WaT = Xb  + (size_t)MM*CC;              // [3072][1024] bf16 (w_attn^T)
  u16* WpT = WaT + (size_t)N3*CC;              // [1024][1024] bf16 (w_proj^T)
  u16* Qh  = WpT + (size_t)CC*CC;              // [B,H,T,D] bf16 (pre-scaled)
  u16* Kh  = Qh  + (size_t)BB*HH*TT*DD;        // [B,H,T,D] bf16
  u16* Vt  = Kh  + (size_t)BB*HH*TT*DD;        // [B,H,D,T] bf16 (transposed)
  u16* Yh  = Vt  + (size_t)BB*HH*TT*DD;        // [8192][1024] bf16

  k_prep<<<dim3(8192), dim3(256), 0, stream>>>(x, w_attn, w_proj, Xb, WaT, WpT);
  k_gemm_qkv<<<dim3((MM/128)*(N3/256)), dim3(512), 0, stream>>>(Xb, WaT, b_attn, Qh, Kh, Vt);
  k_attn<<<dim3(BB*HH*8), dim3(256), 0, stream>>>(Qh, Kh, Vt, Yh);
  k_gemm_proj<<<dim3((MM/128)*(CC/256)), dim3(512), 0, stream>>>(Yh, WpT, b_proj, out);
}